// Round 3
// baseline (202.440 us; speedup 1.0000x reference)
//
#include <hip/hip_runtime.h>
#include <hip/hip_bf16.h>
#include <math.h>

typedef _Float16 f16;
typedef _Float16 f16x4 __attribute__((ext_vector_type(4)));

#define NK 256          // number of kernels
#define LPAD 249        // dense kernel length
#define MAXTAPS 11      // max nonzero taps per kernel
#define TLEN 2000       // time length
#define PAD 124         // (LPAD-1)/2
#define XCOPY_LEN 2304  // per-copy staged length (covers max read index 2295)
#define KPB 32          // kernels per block
#define THREADS 256
#define BC 256          // B*C rows
#define NCHUNK 8        // t-chunks of 256 (64 lanes x 4 consecutive t)

// ---- prep: wave-parallel sparse-tap extraction (1 wave per kernel) ----
__global__ __launch_bounds__(64) void extract_taps(const float* __restrict__ W,
                                                   int* __restrict__ offs,
                                                   float* __restrict__ wgt) {
    const int k    = blockIdx.x;
    const int lane = threadIdx.x;
    int n = 0;  // running count of nonzeros (wave-uniform)
#pragma unroll
    for (int s = 0; s < 4; ++s) {
        const int l = s * 64 + lane;
        const float w = (l < LPAD) ? W[k * LPAD + l] : 0.0f;
        const unsigned long long m = __ballot(w != 0.0f);
        const int pos = n + __popcll(m & ((lane ? ((1ull << lane) - 1) : 0ull)));
        if (w != 0.0f && pos < MAXTAPS) {
            offs[k * MAXTAPS + pos] = l;
            wgt[k * MAXTAPS + pos]  = w;
        }
        n += __popcll(m);
    }
    // pad unused tap slots (harmless zero-weight reads at offset 0)
    for (int i = n + lane; i < MAXTAPS; i += 64) {
        offs[k * MAXTAPS + i] = 0;
        wgt[k * MAXTAPS + i]  = 0.0f;
    }
}

// ---- main: sparse conv (f16 LDS, 4 shifted copies) + ppv/max pooling ----
__global__ __launch_bounds__(THREADS) void rocket_main(
    const float* __restrict__ x,
    const float* __restrict__ bias,
    const int* __restrict__ offs,
    const float* __restrict__ wgt,
    float* __restrict__ out) {
    __shared__ __align__(16) f16 hs[4][XCOPY_LEN];
    __shared__ int   s_o[KPB * MAXTAPS];
    __shared__ float s_w[KPB * MAXTAPS];
    __shared__ float s_b[KPB];

    const int bc    = blockIdx.x;          // 0..255
    const int kbase = blockIdx.y * KPB;    // kernel group base
    const int tid   = threadIdx.x;

    // stage 4 shifted f16 copies: hs[c][i] = X(i + c), X = zero-padded row
    const float* xrow = x + bc * TLEN;
    for (int i = tid; i < XCOPY_LEN; i += THREADS) {
#pragma unroll
        for (int c = 0; c < 4; ++c) {
            const int t = i + c - PAD;
            const float v = (t >= 0 && t < TLEN) ? xrow[t] : 0.0f;
            hs[c][i] = (f16)v;
        }
    }
    for (int i = tid; i < KPB * MAXTAPS; i += THREADS) {
        s_o[i] = offs[kbase * MAXTAPS + i];
        s_w[i] = wgt[kbase * MAXTAPS + i];
    }
    if (tid < KPB) s_b[tid] = bias[kbase + tid];
    __syncthreads();

    const int wid  = tid >> 6;
    const int lane = tid & 63;

    // each wave owns KPB/4 = 8 consecutive kernels
    for (int kk = wid * (KPB / 4); kk < (wid + 1) * (KPB / 4); ++kk) {
        const f16* p[MAXTAPS];
        float      w[MAXTAPS];
#pragma unroll
        for (int j = 0; j < MAXTAPS; ++j) {
            const int o = s_o[kk * MAXTAPS + j];
            w[j] = s_w[kk * MAXTAPS + j];
            p[j] = &hs[o & 3][(o & ~3) + 4 * lane];   // 8B-aligned per lane
        }
        const float b = s_b[kk];

        int   cnt = 0;
        float mx  = -INFINITY;

#pragma unroll
        for (int chunk = 0; chunk < NCHUNK; ++chunk) {
            const int tb = chunk * 256;   // folds into ds_read offset imm
            float a0 = b, a1 = b, a2 = b, a3 = b;
#pragma unroll
            for (int j = 0; j < MAXTAPS; ++j) {
                const f16x4 v = *(const f16x4*)(p[j] + tb);
                const float ww = w[j];
                a0 += ww * (float)v[0];
                a1 += ww * (float)v[1];
                a2 += ww * (float)v[2];
                a3 += ww * (float)v[3];
            }
            // t = tb + 4*lane + q
            if (chunk == NCHUNK - 1) {
                // valid iff 4*lane+q < 208  <=>  lane < 52 (for all q)
                const unsigned long long m = (1ull << 52) - 1;
                cnt += __popcll(__ballot(a0 > 0.0f) & m);
                cnt += __popcll(__ballot(a1 > 0.0f) & m);
                cnt += __popcll(__ballot(a2 > 0.0f) & m);
                cnt += __popcll(__ballot(a3 > 0.0f) & m);
                if (lane >= 52) { a0 = -INFINITY; a1 = -INFINITY; a2 = -INFINITY; a3 = -INFINITY; }
            } else {
                cnt += __popcll(__ballot(a0 > 0.0f));
                cnt += __popcll(__ballot(a1 > 0.0f));
                cnt += __popcll(__ballot(a2 > 0.0f));
                cnt += __popcll(__ballot(a3 > 0.0f));
            }
            mx = fmaxf(mx, fmaxf(fmaxf(a0, a1), fmaxf(a2, a3)));
        }

#pragma unroll
        for (int s = 32; s; s >>= 1) {
            mx = fmaxf(mx, __shfl_xor(mx, s, 64));
        }
        if (lane == 0) {
            const int k = kbase + kk;
            out[bc * (2 * NK) + 2 * k]     = (float)cnt * (1.0f / (float)TLEN);
            out[bc * (2 * NK) + 2 * k + 1] = mx;
        }
    }
}

extern "C" void kernel_launch(void* const* d_in, const int* in_sizes, int n_in,
                              void* d_out, int out_size, void* d_ws, size_t ws_size,
                              hipStream_t stream) {
    const float* x    = (const float*)d_in[0];   // (8,32,2000)
    const float* W    = (const float*)d_in[1];   // (256,249)
    const float* bias = (const float*)d_in[2];   // (256,)
    float* out = (float*)d_out;                  // (8,32,512)

    int*   offs = (int*)d_ws;
    float* wgt  = (float*)((char*)d_ws + NK * MAXTAPS * sizeof(int));

    extract_taps<<<NK, 64, 0, stream>>>(W, offs, wgt);

    dim3 grid(BC, NK / KPB);  // 256 x 8
    rocket_main<<<grid, THREADS, 0, stream>>>(x, bias, offs, wgt, out);
}

// Round 4
// 70.666 us; speedup vs baseline: 2.8647x; 2.8647x over previous
//
#include <hip/hip_runtime.h>
#include <math.h>

typedef _Float16 f16;
typedef _Float16 half4 __attribute__((ext_vector_type(4)));
typedef _Float16 half8 __attribute__((ext_vector_type(8)));
typedef float f32x4 __attribute__((ext_vector_type(4)));

#define NK 256
#define LW 249          // dense kernel length (cols of W)
#define TLEN 2000
#define PAD 124
#define NCOPY 8         // byte-shift copies for b128 alignment
#define CPL 2312        // copy stride in elements (4624B: +4 dwords bank skew/copy)
#define CPWRITE 2304    // staged elements per copy
#define THREADS 512
#define NT_TOTAL 125    // 2000 / 16 exactly -> no tail masking

// One kernel does everything: stage x (f16, 8 shifted copies), load W rows as
// f16 A-fragments, Toeplitz-GEMM via mfma_f32_16x16x32_f16, fused ppv/max pooling.
__global__ __launch_bounds__(THREADS, 2) void rocket_mfma(
    const float* __restrict__ x,
    const float* __restrict__ W,
    const float* __restrict__ bias,
    float* __restrict__ out) {
  __shared__ f16   xc[NCOPY * CPL];
  __shared__ float bufc[NK], bufm[NK];

  const int bc   = blockIdx.x;
  const int tid  = threadIdx.x;
  const int wid  = tid >> 6;
  const int lane = tid & 63;
  const int wm   = wid & 3;    // m-group: 4 m-tiles each (64 k rows)
  const int wn   = wid >> 2;   // n-half: t-tiles [0,63) or [63,125)
  const int l15  = lane & 15;
  const int lq   = lane >> 4;

  // ---- stage 8 shifted f16 copies: xc[c][i] = xpad(i + c), xpad(j)=x[j-PAD] ----
  const float* xrow = x + bc * TLEN;
  for (int q = tid * 4; q < NCOPY * CPWRITE; q += THREADS * 4) {
    const int cpy = q / CPWRITE;
    const int i   = q - cpy * CPWRITE;
    half4 v;
#pragma unroll
    for (int r = 0; r < 4; ++r) {
      const int j = i + r + cpy - PAD;
      v[r] = (j >= 0 && j < TLEN) ? (f16)xrow[j] : (f16)0.0f;
    }
    *(half4*)&xc[cpy * CPL + i] = v;   // 8B-aligned (i % 4 == 0)
  }

  // ---- A fragments: af[mt][kb], lane holds W[row = l15][k = kb*32+8*lq .. +7] ----
  half8 af[4][8];
#pragma unroll
  for (int mt = 0; mt < 4; ++mt) {
    const int row = wm * 64 + mt * 16 + l15;
#pragma unroll
    for (int kb = 0; kb < 8; ++kb) {
      const int l0 = kb * 32 + 8 * lq;
      half8 a;
#pragma unroll
      for (int i = 0; i < 8; ++i) {
        const int ll = l0 + i;
        a[i] = (ll < LW) ? (f16)W[row * LW + ll] : (f16)0.0f;
      }
      af[mt][kb] = a;
    }
  }

  // thresholds: y>0  <=>  c > -bias[k];  k = wm*64 + mt*16 + lq*4 + r (C/D layout)
  float thr[4][4];
#pragma unroll
  for (int mt = 0; mt < 4; ++mt)
#pragma unroll
    for (int r = 0; r < 4; ++r)
      thr[mt][r] = -bias[wm * 64 + mt * 16 + lq * 4 + r];

  __syncthreads();

  // B fragment per-lane base: element e = nt*16 + kb*32 + 8*lq + l15;
  // copy c = l15&7 makes (e - c) 8-element aligned -> single ds_read_b128.
  const int lane_e   = 8 * lq + l15;
  const int cpy_sel  = l15 & 7;
  const int bbase    = cpy_sel * CPL + (lane_e - cpy_sel);

  float cnt[4][4], mx[4][4];
#pragma unroll
  for (int mt = 0; mt < 4; ++mt)
#pragma unroll
    for (int r = 0; r < 4; ++r) { cnt[mt][r] = 0.0f; mx[mt][r] = -INFINITY; }

  const int nt_lo = (wn == 0) ? 0 : 63;
  const int nt_hi = (wn == 0) ? 63 : NT_TOTAL;

  for (int nt = nt_lo; nt < nt_hi; ++nt) {
    f32x4 acc[4];
#pragma unroll
    for (int mt = 0; mt < 4; ++mt) acc[mt] = (f32x4){0.0f, 0.0f, 0.0f, 0.0f};
    const int nb = bbase + nt * 16;
#pragma unroll
    for (int kb = 0; kb < 8; ++kb) {
      const half8 b = *(const half8*)&xc[nb + kb * 32];
#pragma unroll
      for (int mt = 0; mt < 4; ++mt)
        acc[mt] = __builtin_amdgcn_mfma_f32_16x16x32_f16(af[mt][kb], b, acc[mt], 0, 0, 0);
    }
    // fused pooling on raw accumulators (bias folded into thr; added to max at end)
#pragma unroll
    for (int mt = 0; mt < 4; ++mt) {
#pragma unroll
      for (int r = 0; r < 4; ++r) {
        const float v = acc[mt][r];
        cnt[mt][r] += (v > thr[mt][r]) ? 1.0f : 0.0f;
        mx[mt][r]   = fmaxf(mx[mt][r], v);
      }
    }
  }

  // ---- reduce over the 16 lanes sharing each k (width-16 xor shuffles) ----
  float pc[4][4], pm[4][4];
#pragma unroll
  for (int mt = 0; mt < 4; ++mt) {
#pragma unroll
    for (int r = 0; r < 4; ++r) {
      float c0 = cnt[mt][r], m0 = mx[mt][r];
#pragma unroll
      for (int s = 1; s < 16; s <<= 1) {
        c0 += __shfl_xor(c0, s, 16);
        m0  = fmaxf(m0, __shfl_xor(m0, s, 16));
      }
      pc[mt][r] = c0; pm[mt][r] = m0;
    }
  }

  // ---- combine the two n-halves via LDS, then write ----
  if (wn == 0 && l15 == 0) {
#pragma unroll
    for (int mt = 0; mt < 4; ++mt)
#pragma unroll
      for (int r = 0; r < 4; ++r) {
        const int k = wm * 64 + mt * 16 + lq * 4 + r;
        bufc[k] = pc[mt][r];
        bufm[k] = pm[mt][r];
      }
  }
  __syncthreads();
  if (wn == 1 && l15 == 0) {
#pragma unroll
    for (int mt = 0; mt < 4; ++mt)
#pragma unroll
      for (int r = 0; r < 4; ++r) {
        const int k = wm * 64 + mt * 16 + lq * 4 + r;
        const float tc = pc[mt][r] + bufc[k];
        const float tm = fmaxf(pm[mt][r], bufm[k]);
        out[bc * (2 * NK) + 2 * k]     = tc * (1.0f / (float)TLEN);
        out[bc * (2 * NK) + 2 * k + 1] = tm - thr[mt][r];   // + bias[k]
      }
  }
}

extern "C" void kernel_launch(void* const* d_in, const int* in_sizes, int n_in,
                              void* d_out, int out_size, void* d_ws, size_t ws_size,
                              hipStream_t stream) {
  const float* x    = (const float*)d_in[0];   // (8,32,2000)
  const float* W    = (const float*)d_in[1];   // (256,249)
  const float* bias = (const float*)d_in[2];   // (256,)
  float* out = (float*)d_out;                  // (8,32,512)

  rocket_mfma<<<256, THREADS, 0, stream>>>(x, W, bias, out);
}

// Round 5
// 68.979 us; speedup vs baseline: 2.9348x; 1.0245x over previous
//
#include <hip/hip_runtime.h>
#include <math.h>

typedef _Float16 f16;
typedef _Float16 half4 __attribute__((ext_vector_type(4)));
typedef _Float16 half8 __attribute__((ext_vector_type(8)));
typedef float f32x4 __attribute__((ext_vector_type(4)));

#define NK 256
#define LW 249
#define WHS 256          // Wh row stride (f16, zero-padded cols 249..255)
#define TLEN 2000
#define PAD 124
#define NCOPY 8
#define CPL 2328         // elems/copy; dword stride 1164 == 12 mod 32 -> conflict-free b128
#define CPWRITE 2304     // staged elems per copy (max read idx 2295 + pipeline slack)
#define THREADS 512

// ---- prep: W (256,249) f32 -> Wh (256,256) f16, zero-padded ----
__global__ __launch_bounds__(256) void convert_W(const float* __restrict__ W,
                                                 f16* __restrict__ Wh) {
  const int k = blockIdx.x, l = threadIdx.x;
  Wh[k * WHS + l] = (l < LW) ? (f16)W[k * LW + l] : (f16)0.0f;
}

// ---- main: Toeplitz MFMA with sliding-window B-frag register ring ----
__global__ __launch_bounds__(THREADS, 2) void rocket_mfma(
    const float* __restrict__ x,
    const f16*   __restrict__ Wh,
    const float* __restrict__ bias,
    float*       __restrict__ out) {
  __shared__ f16   xc[NCOPY * CPL];
  __shared__ float bufc[NK], bufm[NK];

  const int bc   = blockIdx.x;
  const int tid  = threadIdx.x;
  const int wid  = tid >> 6;
  const int lane = tid & 63;
  const int wm   = wid & 3;     // m-group: rows [wm*64, wm*64+64)
  const int wn   = wid >> 2;    // nt parity: 0 -> even nt, 1 -> odd nt
  const int l15  = lane & 15;
  const int lq   = lane >> 4;

  // ---- stage 8 shifted f16 copies: xc[c][i] = xpad(i + c), xpad(j)=x[j-PAD] ----
  const float* xrow = x + bc * TLEN;
  for (int q = tid * 4; q < NCOPY * CPWRITE; q += THREADS * 4) {
    const int cpy = q / CPWRITE;
    const int i   = q - cpy * CPWRITE;
    half4 v;
#pragma unroll
    for (int r = 0; r < 4; ++r) {
      const int j = i + r + cpy - PAD;
      v[r] = (j >= 0 && j < TLEN) ? (f16)xrow[j] : (f16)0.0f;
    }
    *(half4*)&xc[cpy * CPL + i] = v;
  }

  // ---- A fragments: af[mt][kb], lane holds Wh[row=l15][kb*32+8*lq .. +7] ----
  half8 af[4][8];
#pragma unroll
  for (int mt = 0; mt < 4; ++mt) {
    const int row = wm * 64 + mt * 16 + l15;
#pragma unroll
    for (int kb = 0; kb < 8; ++kb)
      af[mt][kb] = *(const half8*)&Wh[row * WHS + kb * 32 + 8 * lq];
  }

  // thresholds: y>0 <=> acc > -bias[k]; k = wm*64 + mt*16 + lq*4 + r (C layout)
  float thr[4][4];
#pragma unroll
  for (int mt = 0; mt < 4; ++mt)
#pragma unroll
    for (int r = 0; r < 4; ++r)
      thr[mt][r] = -bias[wm * 64 + mt * 16 + lq * 4 + r];

  __syncthreads();

  // per-lane B base: element e(nt,kb) = nt*16 + kb*32 + 8*lq + l15, copy = l15&7
  const int lane_e = 8 * lq + l15;
  const int cpy    = l15 & 7;
  const int b0     = cpy * CPL + (lane_e - cpy) + wn * 16;   // nt0 = wn

  // prologue: fill ring with frag(nt0, kb), kb=0..7
  half8 R[8];
#pragma unroll
  for (int kb = 0; kb < 8; ++kb)
    R[kb] = *(const half8*)&xc[b0 + kb * 32];

  int   cnt[4][4];
  float mx[4][4];
#pragma unroll
  for (int mt = 0; mt < 4; ++mt)
#pragma unroll
    for (int r = 0; r < 4; ++r) { cnt[mt][r] = 0; mx[mt][r] = -INFINITY; }

  // 64 n-tiles per parity stream (incl. 1-2 padded tiles, pooling-masked)
  for (int it = 0; it < 8; ++it) {
#pragma unroll
    for (int ui = 0; ui < 8; ++ui) {
      const int u  = it * 8 + ui;
      const int nt = wn + 2 * u;

      f32x4 acc[4];
#pragma unroll
      for (int mt = 0; mt < 4; ++mt) acc[mt] = (f32x4){0.0f, 0.0f, 0.0f, 0.0f};

#pragma unroll
      for (int kb = 0; kb < 8; ++kb) {
        const half8 b = R[(ui + kb) & 7];   // frag(nt, kb) by ring invariant
#pragma unroll
        for (int mt = 0; mt < 4; ++mt)
          acc[mt] = __builtin_amdgcn_mfma_f32_16x16x32_f16(af[mt][kb], b, acc[mt], 0, 0, 0);
      }

      // slide window: load frag(nt+2, 7) = element nt*16 + 256 into dead slot
      R[ui] = *(const half8*)&xc[b0 + 32 * u + 256];

      if (nt <= 124) {   // t = nt*16 + l15 all valid (2000 = 125*16)
#pragma unroll
        for (int mt = 0; mt < 4; ++mt) {
#pragma unroll
          for (int r = 0; r < 4; ++r) {
            const float v = acc[mt][r];
            cnt[mt][r] += (v > thr[mt][r]) ? 1 : 0;
            mx[mt][r]   = fmaxf(mx[mt][r], v);
          }
        }
      }
    }
  }

  // ---- reduce over 16 lanes sharing each k (width-16 xor shuffles) ----
  float pc[4][4], pm[4][4];
#pragma unroll
  for (int mt = 0; mt < 4; ++mt) {
#pragma unroll
    for (int r = 0; r < 4; ++r) {
      float c0 = (float)cnt[mt][r], m0 = mx[mt][r];
#pragma unroll
      for (int s = 1; s < 16; s <<= 1) {
        c0 += __shfl_xor(c0, s, 16);
        m0  = fmaxf(m0, __shfl_xor(m0, s, 16));
      }
      pc[mt][r] = c0; pm[mt][r] = m0;
    }
  }

  // ---- combine parity halves via LDS, then write ----
  if (wn == 0 && l15 == 0) {
#pragma unroll
    for (int mt = 0; mt < 4; ++mt)
#pragma unroll
      for (int r = 0; r < 4; ++r) {
        const int k = wm * 64 + mt * 16 + lq * 4 + r;
        bufc[k] = pc[mt][r];
        bufm[k] = pm[mt][r];
      }
  }
  __syncthreads();
  if (wn == 1 && l15 == 0) {
#pragma unroll
    for (int mt = 0; mt < 4; ++mt)
#pragma unroll
      for (int r = 0; r < 4; ++r) {
        const int k = wm * 64 + mt * 16 + lq * 4 + r;
        const float tc = pc[mt][r] + bufc[k];
        const float tm = fmaxf(pm[mt][r], bufm[k]);
        out[bc * (2 * NK) + 2 * k]     = tc * (1.0f / (float)TLEN);
        out[bc * (2 * NK) + 2 * k + 1] = tm - thr[mt][r];   // + bias[k]
      }
  }
}

extern "C" void kernel_launch(void* const* d_in, const int* in_sizes, int n_in,
                              void* d_out, int out_size, void* d_ws, size_t ws_size,
                              hipStream_t stream) {
  const float* x    = (const float*)d_in[0];   // (8,32,2000)
  const float* W    = (const float*)d_in[1];   // (256,249)
  const float* bias = (const float*)d_in[2];   // (256,)
  float* out = (float*)d_out;                  // (8,32,512)

  f16* Wh = (f16*)d_ws;                        // 256*256*2B = 128 KiB scratch

  convert_W<<<NK, 256, 0, stream>>>(W, Wh);
  rocket_mfma<<<256, THREADS, 0, stream>>>(x, Wh, bias, out);
}